// Round 7
// baseline (9706.081 us; speedup 1.0000x reference)
//
#include <hip/hip_runtime.h>

// 2-layer LSTM (H=50, B=4096, T=512, D_in=1) + FC(50->1), fused MFMA, round 21.
//
// SPLIT-BLOCK DESIGN: r16 showed the ~650cyc/step idle is block-global (all
// waves phase-locked by the single shared barrier; doubling waves/SIMD cut
// idle by only 65cyc). Fix: TWO independent barrier domains per CU.
//   grid 512 x 512thr: blocks 0..255 = layer-0 for pair=bid (r17/r20 L0 code,
//   8 waves, 13 jobs, LDS H1 ring[4], 1 barrier/step); blocks 256..511 =
//   layer-1 for pair=bid-256 (8 waves, 13 jobs, LDS H2 ring[2], 1 barrier/
//   step), reading h1 frag-lines from a global ring in d_ws (copied verbatim
//   from the LDS frag layout, coalesced 2KB/step), paced by one per-pair
//   release/acquire AGENT flag per step. All 512 blocks are co-resident by
//   capacity (2/CU: 16 waves, ~91KB LDS, <=128 VGPR) -> flow control can't
//   deadlock. bid and bid+256 map to the same XCD (256%8==0) -> ring stays
//   L2-resident. Flags hipMemsetAsync-zeroed each launch (graph-safe).
//   Co-resident blocks have UNCORRELATED phases: one block's barrier tail /
//   post-barrier LDS window fills with the other block's issue.
// Arithmetic is verbatim r20 (same MFMA order, same cell_update) -> absmax
// bit-identical. FALLBACK: if ws_size < 64-step ring (33.6MB), launch the
// r20 fused 16-wave kernel unchanged.
// B-frag layout (r2-r13-verified): k -> ks=k>>5, lane=((k>>3)&3)*16+n, j=k&7.

#define TT 512
#define HH 50
#define BT 16
#define L2E 1.44269504f

typedef _Float16 half8 __attribute__((ext_vector_type(8)));
typedef float floatx4 __attribute__((ext_vector_type(4)));

static __device__ __forceinline__ float fexp2(float x) { return __builtin_amdgcn_exp2f(x); }
static __device__ __forceinline__ float frcp(float x)  { return __builtin_amdgcn_rcpf(x); }

// PRE-SCALED cell update (identical to r17/r20): inputs are s_g*gate
// (s = -log2e, -log2e, -2log2e, -log2e for i,f,g,o).
static __device__ __forceinline__ float cell_update(float gi, float gf, float gg,
                                                    float go, float& c) {
    float Ei = fexp2(gi);
    float Eg = fexp2(gg);
    float Ef = fexp2(gf);
    float Eo = fexp2(go);
    float p1 = (1.0f + Ei) * (1.0f + Eg);
    float fe = 1.0f + Ef;
    float R  = frcp(fe * p1);
    c = R * (c * p1 + (1.0f - Eg) * fe);
    float cl = fminf(fmaxf(c, -18.0f), 18.0f);
    float Ec = fexp2(cl * (-2.0f * L2E));
    float Ro = frcp((1.0f + Eo) * (1.0f + Ec));
    return (1.0f - Ec) * Ro;
}

#define MFMA(a, b, c) __builtin_amdgcn_mfma_f32_16x16x32_f16((a), (b), (c), 0, 0, 0)

// ==================== split path: layer-0 block ====================
// Step s computes h1(s) from h1(s-1) = H1[(s-1)&3]; writes H1[s&3].
// XW wave maintains x slot 51; CP wave exports h1(s-1) to the global ring at
// interval s and publishes prod=s (release, agent scope).
template<int NJ, bool XW, bool CP>
static __device__ __forceinline__ void run_l0s(
    int tbase, int ln, _Float16 (*H1)[1024], const float* xs,
    _Float16* ring, int* prod, const int* cons, int ringm, int rslots,
    const float* __restrict__ W_ih0, const float* __restrict__ W_hh0,
    const float* __restrict__ b_ih0, const float* __restrict__ b_hh0)
{
    const int m = ln & 15, q = ln >> 4;
    const float GSC[4] = { -L2E, -L2E, -2.0f * L2E, -L2E };

    half8 a0[NJ][2];
    float c[NJ];
    int   widx[NJ];
#pragma unroll
    for (int j = 0; j < NJ; ++j) {
        const int  tau  = tbase + j;
        const int  uA   = 4 * tau + (m >> 2);
        const int  gA   = m & 3;
        const bool rokA = (uA < HH);
        const int  wrow = gA * HH + uA;
        const float sA  = GSC[gA];
#pragma unroll
        for (int ks = 0; ks < 2; ++ks) {
            half8 h8;
#pragma unroll
            for (int jj = 0; jj < 8; ++jj) {
                int k = ks * 32 + q * 8 + jj;
                float w = 0.f;
                if (rokA) {
                    if (k < HH)       w = W_hh0[wrow * HH + k];
                    else if (k == 50) w = b_ih0[wrow] + b_hh0[wrow];
                    else if (k == 51) w = W_ih0[wrow];      // W_ih0 is [4H x 1]
                }
                h8[jj] = (_Float16)(sA * w);
            }
            a0[j][ks] = h8;
        }
        const int uC = 4 * tau + q;
        const int kh = (uC < HH) ? uC : (uC + 2);   // dummies 50,51 -> 52,53
        widx[j] = ((kh >> 5) * 64 + ((kh >> 3) & 3) * 16 + m) * 8 + (kh & 7);
        c[j] = 0.f;
    }

    // ---- t = 0: h1(0) from x(0) only (h=0), scalar path -> H1[0] ----
    {
        const float xv = xs[m];
#pragma unroll
        for (int j = 0; j < NJ; ++j) {
            const int  uC = 4 * (tbase + j) + q;
            const bool vC = (uC < HH);
            float g4[4];
#pragma unroll
            for (int g = 0; g < 4; ++g) {
                int rg = g * HH + (vC ? uC : 0);
                g4[g] = vC ? GSC[g] * ((b_ih0[rg] + b_hh0[rg]) + W_ih0[rg] * xv) : 0.f;
            }
            float h = cell_update(g4[0], g4[1], g4[2], g4[3], c[j]);
            H1[0][widx[j]] = (_Float16)h;
        }
    }
    __syncthreads();

    const floatx4 ZERO = { 0.f, 0.f, 0.f, 0.f };
    for (int s = 1; s <= 511; ++s) {
        if (CP) {   // export h1(s-1) -> ring slot (s-1)&ringm, publish prod=s
            while (__hip_atomic_load(cons, __ATOMIC_RELAXED,
                                     __HIP_MEMORY_SCOPE_AGENT) < s - rslots)
                __builtin_amdgcn_s_sleep(2);
            const _Float16* bufE = H1[(s - 1) & 3];
            half8 v0 = *(const half8*)&bufE[ln * 8];
            half8 v1 = *(const half8*)&bufE[512 + ln * 8];
            _Float16* slot = ring + (size_t)((s - 1) & ringm) * 1024;
            *(half8*)(slot + ln * 8) = v0;
            *(half8*)(slot + 512 + ln * 8) = v1;
            if (ln == 0)
                __hip_atomic_store(prod, s, __ATOMIC_RELEASE,
                                   __HIP_MEMORY_SCOPE_AGENT);
        }
        {
            const _Float16* bufR = H1[(s - 1) & 3];
            _Float16*       bufW = H1[s & 3];
            if (XW) {
                if (ln < 16)        // x(s+1) -> slot 51; s=511 reads zero pad
                    bufW[(96 + ln) * 8 + 3] = (_Float16)xs[(s + 1) * BT + ln];
            }
            half8 b0 = *(const half8*)&bufR[ln * 8];
            half8 b1 = *(const half8*)&bufR[512 + ln * 8];
#pragma unroll
            for (int j = 0; j < NJ; ++j) {
                floatx4 a = MFMA(a0[j][0], b0, ZERO);
                a = MFMA(a0[j][1], b1, a);
                float h = cell_update(a[0], a[1], a[2], a[3], c[j]);
                bufW[widx[j]] = (_Float16)h;
            }
        }
        __syncthreads();
    }
    if (CP) {   // tail: export h1(511), publish prod=512
        while (__hip_atomic_load(cons, __ATOMIC_RELAXED,
                                 __HIP_MEMORY_SCOPE_AGENT) < 512 - rslots)
            __builtin_amdgcn_s_sleep(2);
        const _Float16* bufE = H1[3];
        half8 v0 = *(const half8*)&bufE[ln * 8];
        half8 v1 = *(const half8*)&bufE[512 + ln * 8];
        _Float16* slot = ring + (size_t)(511 & ringm) * 1024;
        *(half8*)(slot + ln * 8) = v0;
        *(half8*)(slot + 512 + ln * 8) = v1;
        if (ln == 0)
            __hip_atomic_store(prod, 512, __ATOMIC_RELEASE,
                               __HIP_MEMORY_SCOPE_AGENT);
    }
}

// ==================== split path: layer-1 block ====================
// Step u computes h2(u) from h1(u) (global ring slot u&ringm, gated by
// prod>=u+1) and h2(u-1) = H2[(u+1)&1]; writes H2[u&1]. PB wave publishes
// cons=u+1 after the step barrier (all waves' ring reads consumed by then).
template<int NJ, bool PB>
static __device__ __forceinline__ void run_l1s(
    int tbase, int ln, _Float16 (*H2)[1024],
    const _Float16* ring, const int* prod, int* cons, int ringm,
    const float* __restrict__ W_ih1, const float* __restrict__ W_hh1,
    const float* __restrict__ b_ih1, const float* __restrict__ b_hh1)
{
    const int m = ln & 15, q = ln >> 4;
    const float GSC[4] = { -L2E, -L2E, -2.0f * L2E, -L2E };

    half8 a1[NJ][4];       // virtual K=128: [W_ih1 | bias@50 | 0 | W_hh1@64.. | 0]
    float c[NJ];
    int   widx[NJ];
#pragma unroll
    for (int j = 0; j < NJ; ++j) {
        const int  tau  = tbase + j;
        const int  uA   = 4 * tau + (m >> 2);
        const int  gA   = m & 3;
        const bool rokA = (uA < HH);
        const int  wrow = gA * HH + uA;
        const float sA  = GSC[gA];
#pragma unroll
        for (int ks = 0; ks < 4; ++ks) {
            half8 h8;
#pragma unroll
            for (int jj = 0; jj < 8; ++jj) {
                int k = ks * 32 + q * 8 + jj;
                float w = 0.f;
                if (rokA) {
                    if (k < HH)                      w = W_ih1[wrow * HH + k];
                    else if (k == 50)                w = b_ih1[wrow] + b_hh1[wrow];
                    else if (k >= 64 && k < 64 + HH) w = W_hh1[wrow * HH + (k - 64)];
                }
                h8[jj] = (_Float16)(sA * w);
            }
            a1[j][ks] = h8;
        }
        const int uC = 4 * tau + q;
        const int kh = (uC < HH) ? uC : (uC + 2);   // dummies -> 52,53 (zero-A)
        widx[j] = ((kh >> 5) * 64 + ((kh >> 3) & 3) * 16 + m) * 8 + (kh & 7);
        c[j] = 0.f;
    }

    const floatx4 ZERO = { 0.f, 0.f, 0.f, 0.f };
    for (int u = 0; u <= 511; ++u) {
        while (__hip_atomic_load(prod, __ATOMIC_ACQUIRE,
                                 __HIP_MEMORY_SCOPE_AGENT) < u + 1)
            __builtin_amdgcn_s_sleep(1);
        const _Float16* slot = ring + (size_t)(u & ringm) * 1024;
        half8 p0 = *(const half8*)(slot + ln * 8);
        half8 p1 = *(const half8*)(slot + 512 + ln * 8);
        const _Float16* h2R = H2[(u + 1) & 1];   // == (u-1)&1; zeros at u=0
        _Float16*       h2W = H2[u & 1];
        half8 b2 = *(const half8*)&h2R[ln * 8];
        half8 b3 = *(const half8*)&h2R[512 + ln * 8];
#pragma unroll
        for (int j = 0; j < NJ; ++j) {
            floatx4 a = MFMA(a1[j][0], p0, ZERO);
            a = MFMA(a1[j][1], p1, a);
            a = MFMA(a1[j][2], b2, a);
            a = MFMA(a1[j][3], b3, a);
            float h = cell_update(a[0], a[1], a[2], a[3], c[j]);
            h2W[widx[j]] = (_Float16)h;
        }
        __syncthreads();
        if (PB) {
            if (ln == 0)
                __hip_atomic_store(cons, u + 1, __ATOMIC_RELAXED,
                                   __HIP_MEMORY_SCOPE_AGENT);
        }
    }
}

__global__ __launch_bounds__(512, 4) void lstm_split(
    const float* __restrict__ x,
    const float* __restrict__ W_ih0, const float* __restrict__ W_hh0,
    const float* __restrict__ b_ih0, const float* __restrict__ b_hh0,
    const float* __restrict__ W_ih1, const float* __restrict__ W_hh1,
    const float* __restrict__ b_ih1, const float* __restrict__ b_hh1,
    const float* __restrict__ W_fc,  const float* __restrict__ b_fc,
    float* __restrict__ out, char* __restrict__ ws, int ringm)
{
    __shared__ __align__(16) _Float16 H1[4][1024];   // role 0: h1 ring + bias/x
    __shared__ __align__(16) _Float16 H2[2][1024];   // role 1: h2 ring
    __shared__ float xs[(TT + 1) * BT];              // role 0: x stage + pad

    const int tid  = threadIdx.x;
    const int ln   = tid & 63;
    const int wv   = tid >> 6;             // 0..7
    const int pair = blockIdx.x & 255;
    const int role = blockIdx.x >> 8;      // 0 = L0 block, 1 = L1 block
    const int b0g  = pair * BT;
    const int rslots = ringm + 1;

    int* prod = (int*)(ws + (size_t)pair * 64);
    int* cons = (int*)(ws + 16384 + (size_t)pair * 64);
    _Float16* ring = (_Float16*)(ws + 32768) + (size_t)pair * (size_t)rslots * 1024;

    if (role == 0) {
        // -------- one-time staging --------
        for (int i = tid; i < BT * TT; i += 512) {
            int b = i & 15, t = i >> 4;
            xs[t * BT + b] = x[(size_t)(b0g + b) * TT + t];
        }
        if (tid < BT) xs[TT * BT + tid] = 0.f;
        for (int i = tid; i < 4 * 1024; i += 512) ((_Float16*)H1)[i] = (_Float16)0.f;
        __syncthreads();
        if (tid < 16) {
            // bias slot k=50 (ks=1, lane 32+n, j=2) == 1.0, all 4 ring buffers
#pragma unroll
            for (int r = 0; r < 4; ++r) H1[r][(96 + tid) * 8 + 2] = (_Float16)1.0f;
            // x(1) -> slot k=51 of H1[0] (read by L0 at s=1)
            H1[0][(96 + tid) * 8 + 3] = (_Float16)xs[BT + tid];
        }
        __syncthreads();

        // 13 jobs: w0-4: {2*wv,2*wv+1}; w5: 10; w6: 11 (+x-writer); w7: 12 (+copier)
        if (wv < 5)
            run_l0s<2, false, false>(2 * wv, ln, H1, xs, ring, prod, cons, ringm,
                                     rslots, W_ih0, W_hh0, b_ih0, b_hh0);
        else if (wv == 5)
            run_l0s<1, false, false>(10, ln, H1, xs, ring, prod, cons, ringm,
                                     rslots, W_ih0, W_hh0, b_ih0, b_hh0);
        else if (wv == 6)
            run_l0s<1, true, false>(11, ln, H1, xs, ring, prod, cons, ringm,
                                    rslots, W_ih0, W_hh0, b_ih0, b_hh0);
        else
            run_l0s<1, false, true>(12, ln, H1, xs, ring, prod, cons, ringm,
                                    rslots, W_ih0, W_hh0, b_ih0, b_hh0);
    } else {
        for (int i = tid; i < 2 * 1024; i += 512) ((_Float16*)H2)[i] = (_Float16)0.f;
        __syncthreads();

        // 13 jobs: w0: 10 (+publisher); w1: 11; w2: 12; w3-7: {2*(wv-3), +1}
        // (heavy SIMD differs from role 0 so mixed pairings balance)
        if (wv == 0)
            run_l1s<1, true>(10, ln, H2, ring, prod, cons, ringm,
                             W_ih1, W_hh1, b_ih1, b_hh1);
        else if (wv == 1)
            run_l1s<1, false>(11, ln, H2, ring, prod, cons, ringm,
                              W_ih1, W_hh1, b_ih1, b_hh1);
        else if (wv == 2)
            run_l1s<1, false>(12, ln, H2, ring, prod, cons, ringm,
                              W_ih1, W_hh1, b_ih1, b_hh1);
        else
            run_l1s<2, false>(2 * (wv - 3), ln, H2, ring, prod, cons, ringm,
                              W_ih1, W_hh1, b_ih1, b_hh1);

        // -------- FC epilogue: h2(511) in H2[1] --------
        if (tid < BT) {
            float a = b_fc[0];
            for (int u = 0; u < HH; ++u) {
                int idx = ((u >> 5) * 64 + ((u >> 3) & 3) * 16 + tid) * 8 + (u & 7);
                a = fmaf((float)H2[1][idx], W_fc[u], a);
            }
            out[b0g + tid] = a;
        }
    }
}

// ==================== fallback: r20 fused 16-wave kernel ====================
#define NTHRF 1024

template<int NJ, bool XW>
static __device__ __forceinline__ void run_l0f(
    int tbase, int ln, _Float16 (*H1)[1024], const float* xs,
    const float* __restrict__ W_ih0, const float* __restrict__ W_hh0,
    const float* __restrict__ b_ih0, const float* __restrict__ b_hh0)
{
    const int m = ln & 15, q = ln >> 4;
    const float GSC[4] = { -L2E, -L2E, -2.0f * L2E, -L2E };
    half8 a0[NJ][2];
    float c[NJ];
    int   widx[NJ];
#pragma unroll
    for (int j = 0; j < NJ; ++j) {
        const int  tau  = tbase + j;
        const int  uA   = 4 * tau + (m >> 2);
        const int  gA   = m & 3;
        const bool rokA = (uA < HH);
        const int  wrow = gA * HH + uA;
        const float sA  = GSC[gA];
#pragma unroll
        for (int ks = 0; ks < 2; ++ks) {
            half8 h8;
#pragma unroll
            for (int jj = 0; jj < 8; ++jj) {
                int k = ks * 32 + q * 8 + jj;
                float w = 0.f;
                if (rokA) {
                    if (k < HH)       w = W_hh0[wrow * HH + k];
                    else if (k == 50) w = b_ih0[wrow] + b_hh0[wrow];
                    else if (k == 51) w = W_ih0[wrow];
                }
                h8[jj] = (_Float16)(sA * w);
            }
            a0[j][ks] = h8;
        }
        const int uC = 4 * tau + q;
        const int kh = (uC < HH) ? uC : (uC + 2);
        widx[j] = ((kh >> 5) * 64 + ((kh >> 3) & 3) * 16 + m) * 8 + (kh & 7);
        c[j] = 0.f;
    }
    __syncthreads();
    {
        const float xv = xs[m];
#pragma unroll
        for (int j = 0; j < NJ; ++j) {
            const int  uC = 4 * (tbase + j) + q;
            const bool vC = (uC < HH);
            float g4[4];
#pragma unroll
            for (int g = 0; g < 4; ++g) {
                int rg = g * HH + (vC ? uC : 0);
                g4[g] = vC ? GSC[g] * ((b_ih0[rg] + b_hh0[rg]) + W_ih0[rg] * xv) : 0.f;
            }
            float h = cell_update(g4[0], g4[1], g4[2], g4[3], c[j]);
            H1[0][widx[j]] = (_Float16)h;
        }
    }
    __syncthreads();
    const floatx4 ZERO = { 0.f, 0.f, 0.f, 0.f };
    for (int s = 1; s <= 513; ++s) {
        if (s <= 511) {
            const _Float16* bufR = H1[(s - 1) & 3];
            _Float16*       bufW = H1[s & 3];
            if (XW) {
                if (ln < 16)
                    bufW[(96 + ln) * 8 + 3] = (_Float16)xs[(s + 1) * BT + ln];
            }
            half8 b0 = *(const half8*)&bufR[ln * 8];
            half8 b1 = *(const half8*)&bufR[512 + ln * 8];
#pragma unroll
            for (int j = 0; j < NJ; ++j) {
                floatx4 a = MFMA(a0[j][0], b0, ZERO);
                a = MFMA(a0[j][1], b1, a);
                float h = cell_update(a[0], a[1], a[2], a[3], c[j]);
                bufW[widx[j]] = (_Float16)h;
            }
        }
        __syncthreads();
    }
}

template<int NJ>
static __device__ __forceinline__ void run_l1f(
    int tbase, int ln, _Float16 (*H1)[1024], _Float16 (*H2)[1024],
    const float* __restrict__ W_ih1, const float* __restrict__ W_hh1,
    const float* __restrict__ b_ih1, const float* __restrict__ b_hh1)
{
    const int m = ln & 15, q = ln >> 4;
    const float GSC[4] = { -L2E, -L2E, -2.0f * L2E, -L2E };
    half8 a1[NJ][4];
    float c[NJ];
    int   widx[NJ];
#pragma unroll
    for (int j = 0; j < NJ; ++j) {
        const int  tau  = tbase + j;
        const int  uA   = 4 * tau + (m >> 2);
        const int  gA   = m & 3;
        const bool rokA = (uA < HH);
        const int  wrow = gA * HH + uA;
        const float sA  = GSC[gA];
#pragma unroll
        for (int ks = 0; ks < 4; ++ks) {
            half8 h8;
#pragma unroll
            for (int jj = 0; jj < 8; ++jj) {
                int k = ks * 32 + q * 8 + jj;
                float w = 0.f;
                if (rokA) {
                    if (k < HH)                      w = W_ih1[wrow * HH + k];
                    else if (k == 50)                w = b_ih1[wrow] + b_hh1[wrow];
                    else if (k >= 64 && k < 64 + HH) w = W_hh1[wrow * HH + (k - 64)];
                }
                h8[jj] = (_Float16)(sA * w);
            }
            a1[j][ks] = h8;
        }
        const int uC = 4 * tau + q;
        const int kh = (uC < HH) ? uC : (uC + 2);
        widx[j] = ((kh >> 5) * 64 + ((kh >> 3) & 3) * 16 + m) * 8 + (kh & 7);
        c[j] = 0.f;
    }
    __syncthreads();
    __syncthreads();
    half8 p0 = {}, p1 = {};
    const floatx4 ZERO = { 0.f, 0.f, 0.f, 0.f };
    for (int s = 1; s <= 513; ++s) {
        if (s >= 2) {
            const _Float16* h2R = H2[(s - 1) & 1];
            _Float16*       h2W = H2[s & 1];
            half8 b2 = *(const half8*)&h2R[ln * 8];
            half8 b3 = *(const half8*)&h2R[512 + ln * 8];
#pragma unroll
            for (int j = 0; j < NJ; ++j) {
                floatx4 a = MFMA(a1[j][0], p0, ZERO);
                a = MFMA(a1[j][1], p1, a);
                a = MFMA(a1[j][2], b2, a);
                a = MFMA(a1[j][3], b3, a);
                float h = cell_update(a[0], a[1], a[2], a[3], c[j]);
                h2W[widx[j]] = (_Float16)h;
            }
        }
        {
            const _Float16* h1R = H1[(s - 1) & 3];
            p0 = *(const half8*)&h1R[ln * 8];
            p1 = *(const half8*)&h1R[512 + ln * 8];
        }
        __syncthreads();
    }
}

__global__ __launch_bounds__(NTHRF, 4) void lstm_fused(
    const float* __restrict__ x,
    const float* __restrict__ W_ih0, const float* __restrict__ W_hh0,
    const float* __restrict__ b_ih0, const float* __restrict__ b_hh0,
    const float* __restrict__ W_ih1, const float* __restrict__ W_hh1,
    const float* __restrict__ b_ih1, const float* __restrict__ b_hh1,
    const float* __restrict__ W_fc,  const float* __restrict__ b_fc,
    float* __restrict__ out)
{
    __shared__ __align__(16) _Float16 H1[4][1024];
    __shared__ __align__(16) _Float16 H2[2][1024];
    __shared__ float xs[(TT + 1) * BT];

    const int tid = threadIdx.x;
    const int ln  = tid & 63;
    const int wv  = tid >> 6;
    const int b0g = blockIdx.x * BT;

    for (int i = tid; i < BT * TT; i += NTHRF) {
        int b = i & 15, t = i >> 4;
        xs[t * BT + b] = x[(size_t)(b0g + b) * TT + t];
    }
    if (tid < BT) xs[TT * BT + tid] = 0.f;
    for (int i = tid; i < 4 * 1024; i += NTHRF) ((_Float16*)H1)[i] = (_Float16)0.f;
    for (int i = tid; i < 2 * 1024; i += NTHRF) ((_Float16*)H2)[i] = (_Float16)0.f;
    __syncthreads();
    if (tid < 16) {
#pragma unroll
        for (int r = 0; r < 4; ++r) H1[r][(96 + tid) * 8 + 2] = (_Float16)1.0f;
        H1[0][(96 + tid) * 8 + 3] = (_Float16)xs[BT + tid];
    }

    if (wv < 8) {
        if (wv < 5)
            run_l0f<2, false>(2 * wv, ln, H1, xs, W_ih0, W_hh0, b_ih0, b_hh0);
        else if (wv == 6)
            run_l0f<1, true>(11, ln, H1, xs, W_ih0, W_hh0, b_ih0, b_hh0);
        else
            run_l0f<1, false>(wv == 5 ? 10 : 12, ln, H1, xs,
                              W_ih0, W_hh0, b_ih0, b_hh0);
    } else {
        const int w = wv - 8;
        if (w < 3)
            run_l1f<1>(w, ln, H1, H2, W_ih1, W_hh1, b_ih1, b_hh1);
        else
            run_l1f<2>(3 + 2 * (w - 3), ln, H1, H2,
                       W_ih1, W_hh1, b_ih1, b_hh1);
    }

    if (tid < BT) {
        float a = b_fc[0];
        for (int u = 0; u < HH; ++u) {
            int idx = ((u >> 5) * 64 + ((u >> 3) & 3) * 16 + tid) * 8 + (u & 7);
            a = fmaf((float)H2[1][idx], W_fc[u], a);
        }
        out[b0g + tid] = a;
    }
}

extern "C" void kernel_launch(void* const* d_in, const int* in_sizes, int n_in,
                              void* d_out, int out_size, void* d_ws, size_t ws_size,
                              hipStream_t stream) {
    const float* x     = (const float*)d_in[0];
    const float* W_ih0 = (const float*)d_in[1];
    const float* W_hh0 = (const float*)d_in[2];
    const float* b_ih0 = (const float*)d_in[3];
    const float* b_hh0 = (const float*)d_in[4];
    const float* W_ih1 = (const float*)d_in[5];
    const float* W_hh1 = (const float*)d_in[6];
    const float* b_ih1 = (const float*)d_in[7];
    const float* b_hh1 = (const float*)d_in[8];
    const float* W_fc  = (const float*)d_in[9];
    const float* b_fc  = (const float*)d_in[10];
    float* out = (float*)d_out;

    // ring sizing: 32KB flags + 256 pairs x rslots x 2KB
    int rslots = 0;
    if (d_ws && ws_size > 32768) {
        size_t avail = (ws_size - 32768) / (256ull * 2048ull);
        if (avail >= 1) {
            rslots = 1;
            while ((size_t)rslots * 2 <= avail && rslots < 512) rslots *= 2;
        }
    }

    if (rslots >= 64) {
        hipMemsetAsync(d_ws, 0, 32768, stream);      // zero prod/cons flags
        dim3 grid(512), block(512);
        lstm_split<<<grid, block, 0, stream>>>(x, W_ih0, W_hh0, b_ih0, b_hh0,
                                               W_ih1, W_hh1, b_ih1, b_hh1,
                                               W_fc, b_fc, out,
                                               (char*)d_ws, rslots - 1);
    } else {
        dim3 grid(4096 / BT);   // 256 blocks = 1/CU
        dim3 block(NTHRF);      // 16 waves
        lstm_fused<<<grid, block, 0, stream>>>(x, W_ih0, W_hh0, b_ih0, b_hh0,
                                               W_ih1, W_hh1, b_ih1, b_hh1,
                                               W_fc, b_fc, out);
    }
}

// Round 8
// 363.605 us; speedup vs baseline: 26.6941x; 26.6941x over previous
//
#include <hip/hip_runtime.h>

// 2-layer LSTM (H=50, B=4096, T=512, D_in=1) + FC(50->1), fused MFMA, round 22.
//
// = round-20 EXACTLY (the champion: 16 layer-specialized waves, x/bias in
// K-slots, gate pre-scaling, merged-rcp cell, H1 ring[4]/H2 ring[2], one
// s_barrier/step, per-job fused MFMA->update) + ONE change: persistent
// s_setprio(1) on the NJ=2 (two-job) waves.
//
// Ledger: r21's global-ring split-block was catastrophic (9.7ms; agent-scope
// release/acquire + HBM round trip in the serial chain; FETCH 4.6MB->200MB).
// r18/r19 LDS-flag sync lost to s_barrier. r16 TLP +2%, r17 prefetch +1%,
// r20 reorder 0%. Issue-floor model now tight: ~950 cyc/SIMD/step VALU+trans
// issue (measured busy ~970) vs wall ~1590 -> ~620 bubble = barrier mechanics
// + slowest-SIMD trans-chain tail, re-incurred 513x (per-step all-to-all is
// forced by dense W_hh + 16 batches/CU).
// r22 probes the one untested mechanism: the interval tail is defined by the
// heavy (NJ=2) waves; persistent prio-1 on them biases SIMD issue arbitration
// so light (NJ=1) waves fill gaps instead of delaying the tail (T5 mechanism;
// applicable: real role diversity L0/L1 x 1-job/2-job, unlike m190's
// lockstep null). Zero arithmetic change -> absmax bit-identical.
// B-frag layout (r2-r13-verified): k -> ks=k>>5, lane=((k>>3)&3)*16+n, j=k&7.

#define TT 512
#define HH 50
#define BT 16
#define NTHR 1024  // 16 waves
#define L2E 1.44269504f

typedef _Float16 half8 __attribute__((ext_vector_type(8)));
typedef float floatx4 __attribute__((ext_vector_type(4)));

static __device__ __forceinline__ float fexp2(float x) { return __builtin_amdgcn_exp2f(x); }
static __device__ __forceinline__ float frcp(float x)  { return __builtin_amdgcn_rcpf(x); }

// PRE-SCALED cell update: inputs are already s_g*gate (s = -log2e, -log2e,
// -2log2e, -log2e for i,f,g,o). c' = R*[c*(1+Ei)(1+Eg) + (1-Eg)(1+Ef)],
// R = rcp((1+Ef)(1+Ei)(1+Eg)); h = sig(o)*tanh(c'), c clamped (NaN guard).
static __device__ __forceinline__ float cell_update(float gi, float gf, float gg,
                                                    float go, float& c) {
    float Ei = fexp2(gi);
    float Eg = fexp2(gg);
    float Ef = fexp2(gf);
    float Eo = fexp2(go);
    float p1 = (1.0f + Ei) * (1.0f + Eg);
    float fe = 1.0f + Ef;
    float R  = frcp(fe * p1);
    c = R * (c * p1 + (1.0f - Eg) * fe);
    float cl = fminf(fmaxf(c, -18.0f), 18.0f);
    float Ec = fexp2(cl * (-2.0f * L2E));
    float Ro = frcp((1.0f + Eo) * (1.0f + Ec));
    return (1.0f - Ec) * Ro;
}

#define MFMA(a, b, c) __builtin_amdgcn_mfma_f32_16x16x32_f16((a), (b), (c), 0, 0, 0)

// ---------------- layer-0 waves: NJ tile-jobs, tiles tbase..tbase+NJ-1 ----------------
// Iter s computes h1(s) from h1(s-1) = H1[(s-1)&3]; writes H1[s&3].
// XW wave maintains x slot 51 of H1[s&3] with x(s+1).
template<int NJ, bool XW>
static __device__ __forceinline__ void run_l0(
    int tbase, int ln, _Float16 (*H1)[1024], const float* xs,
    const float* __restrict__ W_ih0, const float* __restrict__ W_hh0,
    const float* __restrict__ b_ih0, const float* __restrict__ b_hh0)
{
    const int m = ln & 15, q = ln >> 4;
    const float GSC[4] = { -L2E, -L2E, -2.0f * L2E, -L2E };

    half8 a0[NJ][2];
    float c[NJ];
    int   widx[NJ];
#pragma unroll
    for (int j = 0; j < NJ; ++j) {
        const int  tau  = tbase + j;
        const int  uA   = 4 * tau + (m >> 2);
        const int  gA   = m & 3;
        const bool rokA = (uA < HH);
        const int  wrow = gA * HH + uA;
        const float sA  = GSC[gA];
#pragma unroll
        for (int ks = 0; ks < 2; ++ks) {
            half8 h8;
#pragma unroll
            for (int jj = 0; jj < 8; ++jj) {
                int k = ks * 32 + q * 8 + jj;
                float w = 0.f;
                if (rokA) {
                    if (k < HH)       w = W_hh0[wrow * HH + k];
                    else if (k == 50) w = b_ih0[wrow] + b_hh0[wrow];
                    else if (k == 51) w = W_ih0[wrow];      // W_ih0 is [4H x 1]
                }
                h8[jj] = (_Float16)(sA * w);
            }
            a0[j][ks] = h8;
        }
        const int uC = 4 * tau + q;
        const int kh = (uC < HH) ? uC : (uC + 2);   // dummies 50,51 -> 52,53
        widx[j] = ((kh >> 5) * 64 + ((kh >> 3) & 3) * 16 + m) * 8 + (kh & 7);
        c[j] = 0.f;
    }

    // tail-defining waves get persistent issue priority (interval ends at the
    // slowest wave; light NJ=1 waves have slack and fill the gaps)
    if (NJ == 2) __builtin_amdgcn_s_setprio(1);

    __syncthreads();                       // A: staging + special slots visible

    // ---- t = 0: h1(0) from x(0) only (h=0), scalar path -> H1[0] ----
    {
        const float xv = xs[m];
#pragma unroll
        for (int j = 0; j < NJ; ++j) {
            const int  uC = 4 * (tbase + j) + q;
            const bool vC = (uC < HH);
            float g4[4];
#pragma unroll
            for (int g = 0; g < 4; ++g) {
                int rg = g * HH + (vC ? uC : 0);
                g4[g] = vC ? GSC[g] * ((b_ih0[rg] + b_hh0[rg]) + W_ih0[rg] * xv) : 0.f;
            }
            float h = cell_update(g4[0], g4[1], g4[2], g4[3], c[j]);
            H1[0][widx[j]] = (_Float16)h;
        }
    }
    __syncthreads();                       // B

    const floatx4 ZERO = { 0.f, 0.f, 0.f, 0.f };
    for (int s = 1; s <= 513; ++s) {
        if (s <= 511) {
            const _Float16* bufR = H1[(s - 1) & 3];
            _Float16*       bufW = H1[s & 3];
            if (XW) {
                if (ln < 16)            // x(s+1) -> slot 51; s=511 reads zero pad
                    bufW[(96 + ln) * 8 + 3] = (_Float16)xs[(s + 1) * BT + ln];
            }
            half8 b0 = *(const half8*)&bufR[(0  + ln) * 8];
            half8 b1 = *(const half8*)&bufR[(64 + ln) * 8];
#pragma unroll
            for (int j = 0; j < NJ; ++j) {      // fused: MFMA_j -> update_j -> write_j
                floatx4 a = MFMA(a0[j][0], b0, ZERO);
                a = MFMA(a0[j][1], b1, a);
                float h = cell_update(a[0], a[1], a[2], a[3], c[j]);
                bufW[widx[j]] = (_Float16)h;
            }
        }
        __syncthreads();
    }
}

// ---------------- layer-1 waves: NJ tile-jobs, tiles tbase..tbase+NJ-1 ----------------
// Iter s computes h2(s-2) from h1(s-2) (PREFETCHED last iter into p0,p1) and
// h2(s-3) = H2[(s-1)&1]; writes H2[s&1]. End of iter prefetches h1(s-1).
template<int NJ>
static __device__ __forceinline__ void run_l1(
    int tbase, int ln, _Float16 (*H1)[1024], _Float16 (*H2)[1024],
    const float* __restrict__ W_ih1, const float* __restrict__ W_hh1,
    const float* __restrict__ b_ih1, const float* __restrict__ b_hh1)
{
    const int m = ln & 15, q = ln >> 4;
    const float GSC[4] = { -L2E, -L2E, -2.0f * L2E, -L2E };

    half8 a1[NJ][4];       // virtual K=128: [W_ih1 | bias@50 | 0 | W_hh1@64.. | 0]
    float c[NJ];
    int   widx[NJ];
#pragma unroll
    for (int j = 0; j < NJ; ++j) {
        const int  tau  = tbase + j;
        const int  uA   = 4 * tau + (m >> 2);
        const int  gA   = m & 3;
        const bool rokA = (uA < HH);
        const int  wrow = gA * HH + uA;
        const float sA  = GSC[gA];
#pragma unroll
        for (int ks = 0; ks < 4; ++ks) {
            half8 h8;
#pragma unroll
            for (int jj = 0; jj < 8; ++jj) {
                int k = ks * 32 + q * 8 + jj;
                float w = 0.f;
                if (rokA) {
                    if (k < HH)                      w = W_ih1[wrow * HH + k];
                    else if (k == 50)                w = b_ih1[wrow] + b_hh1[wrow];
                    else if (k >= 64 && k < 64 + HH) w = W_hh1[wrow * HH + (k - 64)];
                }
                h8[jj] = (_Float16)(sA * w);
            }
            a1[j][ks] = h8;
        }
        const int uC = 4 * tau + q;
        const int kh = (uC < HH) ? uC : (uC + 2);   // dummies -> 52,53 (zero-A)
        widx[j] = ((kh >> 5) * 64 + ((kh >> 3) & 3) * 16 + m) * 8 + (kh & 7);
        c[j] = 0.f;
    }

    if (NJ == 2) __builtin_amdgcn_s_setprio(1);

    __syncthreads();                       // A
    __syncthreads();                       // B (L0 prologue)

    half8 p0 = {}, p1 = {};                // prefetched h1 B-frags
    const floatx4 ZERO = { 0.f, 0.f, 0.f, 0.f };
    for (int s = 1; s <= 513; ++s) {
        if (s >= 2) {
            const _Float16* h2R = H2[(s - 1) & 1];
            _Float16*       h2W = H2[s & 1];
            half8 b2 = *(const half8*)&h2R[(0  + ln) * 8];
            half8 b3 = *(const half8*)&h2R[(64 + ln) * 8];
#pragma unroll
            for (int j = 0; j < NJ; ++j) {      // fused: MFMA_j -> update_j -> write_j
                floatx4 a = MFMA(a1[j][0], p0, ZERO);   // p0/p1 in regs: no LDS wait
                a = MFMA(a1[j][1], p1, a);
                a = MFMA(a1[j][2], b2, a);
                a = MFMA(a1[j][3], b3, a);
                float h = cell_update(a[0], a[1], a[2], a[3], c[j]);
                h2W[widx[j]] = (_Float16)h;
            }
        }
        {   // prefetch h1(s-1) for next iter (valid: written before barrier(s-1);
            // reads complete pre-barrier via the compiler's lgkmcnt(0) drain)
            const _Float16* h1R = H1[(s - 1) & 3];
            p0 = *(const half8*)&h1R[(0  + ln) * 8];
            p1 = *(const half8*)&h1R[(64 + ln) * 8];
        }
        __syncthreads();
    }
}

__global__ __launch_bounds__(NTHR, 4) void lstm_mfma(
    const float* __restrict__ x,
    const float* __restrict__ W_ih0, const float* __restrict__ W_hh0,
    const float* __restrict__ b_ih0, const float* __restrict__ b_hh0,
    const float* __restrict__ W_ih1, const float* __restrict__ W_hh1,
    const float* __restrict__ b_ih1, const float* __restrict__ b_hh1,
    const float* __restrict__ W_fc,  const float* __restrict__ b_fc,
    float* __restrict__ out)
{
    __shared__ __align__(16) _Float16 H1[4][1024];   // h1 ring + bias/x slots
    __shared__ __align__(16) _Float16 H2[2][1024];   // h2 ring
    __shared__ float xs[(TT + 1) * BT];              // +1 zero pad row

    const int tid = threadIdx.x;
    const int ln  = tid & 63;
    const int wv  = tid >> 6;              // 0..15
    const int b0g = blockIdx.x * BT;

    // ---------------- one-time staging ----------------
    for (int i = tid; i < BT * TT; i += NTHR) {
        int b = i & 15, t = i >> 4;
        xs[t * BT + b] = x[(size_t)(b0g + b) * TT + t];
    }
    if (tid < BT) xs[TT * BT + tid] = 0.f;
    for (int i = tid; i < 4 * 1024; i += NTHR) ((_Float16*)H1)[i] = (_Float16)0.f;
    for (int i = tid; i < 2 * 1024; i += NTHR) ((_Float16*)H2)[i] = (_Float16)0.f;
    __syncthreads();
    if (tid < 16) {
        // bias slot k=50 (ks=1, lane 32+n, j=2) == 1.0, all 4 ring buffers
#pragma unroll
        for (int r = 0; r < 4; ++r) H1[r][(96 + tid) * 8 + 2] = (_Float16)1.0f;
        // x(1) -> slot k=51 of H1[0] (read by L0 at s=1)
        H1[0][(96 + tid) * 8 + 3] = (_Float16)xs[BT + tid];
    }
    // (visibility of the above: covered by run_*'s first __syncthreads)

    // job split (13 L0 jobs on waves 0-7, 13 L1 jobs on waves 8-15), chosen so
    // round-robin wave->SIMD (wv&3) gives per-SIMD update counts {7,6,6,7}:
    //   L0: w0-w4: 2 jobs; w5, w6(x-writer), w7: 1 job
    //   L1: w8,w9,w10: 1 job; w11-w15: 2 jobs
    if (wv < 8) {
        if (wv < 5)
            run_l0<2, false>(2 * wv, ln, H1, xs, W_ih0, W_hh0, b_ih0, b_hh0);
        else if (wv == 6)
            run_l0<1, true>(11, ln, H1, xs, W_ih0, W_hh0, b_ih0, b_hh0);
        else
            run_l0<1, false>(wv == 5 ? 10 : 12, ln, H1, xs,
                             W_ih0, W_hh0, b_ih0, b_hh0);
    } else {
        const int w = wv - 8;
        if (w < 3)
            run_l1<1>(w, ln, H1, H2, W_ih1, W_hh1, b_ih1, b_hh1);
        else
            run_l1<2>(3 + 2 * (w - 3), ln, H1, H2,
                      W_ih1, W_hh1, b_ih1, b_hh1);
    }

    // -------- FC epilogue: h2(511) written at iter 513 -> H2[1] --------
    if (tid < BT) {
        float a = b_fc[0];
        for (int u = 0; u < HH; ++u) {
            int idx = ((u >> 5) * 64 + ((u >> 3) & 3) * 16 + tid) * 8 + (u & 7);
            a = fmaf((float)H2[1][idx], W_fc[u], a);
        }
        out[b0g + tid] = a;
    }
}

extern "C" void kernel_launch(void* const* d_in, const int* in_sizes, int n_in,
                              void* d_out, int out_size, void* d_ws, size_t ws_size,
                              hipStream_t stream) {
    const float* x     = (const float*)d_in[0];
    const float* W_ih0 = (const float*)d_in[1];
    const float* W_hh0 = (const float*)d_in[2];
    const float* b_ih0 = (const float*)d_in[3];
    const float* b_hh0 = (const float*)d_in[4];
    const float* W_ih1 = (const float*)d_in[5];
    const float* W_hh1 = (const float*)d_in[6];
    const float* b_ih1 = (const float*)d_in[7];
    const float* b_hh1 = (const float*)d_in[8];
    const float* W_fc  = (const float*)d_in[9];
    const float* b_fc  = (const float*)d_in[10];
    float* out = (float*)d_out;

    dim3 grid(4096 / BT);   // 256 blocks = 1/CU
    dim3 block(NTHR);       // 16 waves
    lstm_mfma<<<grid, block, 0, stream>>>(x, W_ih0, W_hh0, b_ih0, b_hh0,
                                          W_ih1, W_hh1, b_ih1, b_hh1,
                                          W_fc, b_fc, out);
}

// Round 9
// 350.164 us; speedup vs baseline: 27.7187x; 1.0384x over previous
//
#include <hip/hip_runtime.h>

// 2-layer LSTM (H=50, B=4096, T=512, D_in=1) + FC(50->1), fused MFMA, round 23.
//
// UNIFIED K=128 OPERAND. r15-r22 ledger: 16-wave structure walled at ~1580
// cyc/step = ~950 issue (critical SIMD: 7 update-calls) + ~620 chain/barrier.
// This round changes the WORK PARTITION, not the schedule:
//   HS ring[2] x 4KB: K-slots 0-49 h1, 50 bias(=1.0), 51 x(t), 64-113 h2.
//   At step s every wave reads the SAME buffer HS[(s-1)&1]: L0 tiles use
//   b0,b1 (h1+bias+x); L1 tiles use b0..b3 (h1 at k<64 via W_ih1, h2 at
//   k>=64 via W_hh1) -> L1 computes h2(s-1) with a 1-step lag, FC reads
//   h2(511) after step 512. Writes all go to HS[s&1]; ring[2] + 1 barrier
//   per step is race-free (buffer written at s is only read at s+1).
//   Unification lets the two half-tiles (units 48/49 of each layer) MERGE
//   into one mixed tile (rows q<2: L0 u48+q; q>=2: L1 u46+q) -> 25
//   update-calls (was 26, no dummy lanes), SIMD load {7,6,6,6}, and 8 waves
//   (512thr) suffice: barrier skew halves, post-barrier LDS reads 48->26,
//   2 waves/SIMD each with 3-4 independent MFMA->update chains.
// Bit-identical arithmetic: L0 rows' extra MFMAs multiply A=0 (adding +-0
// never changes an f32 acc); per-element op order unchanged.
// B-frag layout (r2-r13-verified): k -> ks=k>>5, lane=((k>>3)&3)*16+n, j=k&7.

#define TT 512
#define HH 50
#define BT 16
#define NTHR 512   // 8 waves
#define L2E 1.44269504f

typedef _Float16 half8 __attribute__((ext_vector_type(8)));
typedef float floatx4 __attribute__((ext_vector_type(4)));

static __device__ __forceinline__ float fexp2(float x) { return __builtin_amdgcn_exp2f(x); }
static __device__ __forceinline__ float frcp(float x)  { return __builtin_amdgcn_rcpf(x); }

// PRE-SCALED cell update (identical to r20/r22): inputs are s_g*gate
// (s = -log2e, -log2e, -2log2e, -log2e for i,f,g,o).
// c' = R*[c*(1+Ei)(1+Eg) + (1-Eg)(1+Ef)], R = rcp((1+Ef)(1+Ei)(1+Eg));
// h = sig(o)*tanh(c'), c clamped (NaN guard).
static __device__ __forceinline__ float cell_update(float gi, float gf, float gg,
                                                    float go, float& c) {
    float Ei = fexp2(gi);
    float Eg = fexp2(gg);
    float Ef = fexp2(gf);
    float Eo = fexp2(go);
    float p1 = (1.0f + Ei) * (1.0f + Eg);
    float fe = 1.0f + Ef;
    float R  = frcp(fe * p1);
    c = R * (c * p1 + (1.0f - Eg) * fe);
    float cl = fminf(fmaxf(c, -18.0f), 18.0f);
    float Ec = fexp2(cl * (-2.0f * L2E));
    float Ro = frcp((1.0f + Eo) * (1.0f + Ec));
    return (1.0f - Ec) * Ro;
}

#define MFMA(a, b, c) __builtin_amdgcn_mfma_f32_16x16x32_f16((a), (b), (c), 0, 0, 0)

static __device__ __forceinline__ int widx_of(int unit, int m) {
    return ((unit >> 5) * 64 + ((unit >> 3) & 3) * 16 + m) * 8 + (unit & 7);
}

// One wave: NL0 pure-L0 tiles (l0base..), NL1 pure-L1 tiles (l1base..),
// optional mixed tile (L0 u48/49 on lane-quads 0-1, L1 u48/49 on quads 2-3).
// XW wave maintains x slot 51. PRIO: persistent setprio(1) (7-update SIMD).
template<int NL0, int NL1, bool MX, bool XW, bool PRIO>
static __device__ __forceinline__ void run(
    int l0base, int l1base, int ln, _Float16 (*HS)[2048], const float* xs,
    const float* __restrict__ W_ih0, const float* __restrict__ W_hh0,
    const float* __restrict__ b_ih0, const float* __restrict__ b_hh0,
    const float* __restrict__ W_ih1, const float* __restrict__ W_hh1,
    const float* __restrict__ b_ih1, const float* __restrict__ b_hh1)
{
    const int m = ln & 15, q = ln >> 4;
    const float GSC[4] = { -L2E, -L2E, -2.0f * L2E, -L2E };
    const int  gA = m & 3;
    const float sA = GSC[gA];

    // ---- A-fragments ----
    half8 a0[NL0 ? NL0 : 1][2];            // L0: virtual K 0-63 only
    float c0[NL0 ? NL0 : 1];
    int   w0i[NL0 ? NL0 : 1];
#pragma unroll
    for (int j = 0; j < NL0; ++j) {
        const int uA = 4 * (l0base + j) + (m >> 2);   // <= 47, always valid
        const int wrow = gA * HH + uA;
#pragma unroll
        for (int ks = 0; ks < 2; ++ks) {
            half8 h8;
#pragma unroll
            for (int jj = 0; jj < 8; ++jj) {
                int k = ks * 32 + q * 8 + jj;
                float w = 0.f;
                if (k < HH)       w = W_hh0[wrow * HH + k];
                else if (k == 50) w = b_ih0[wrow] + b_hh0[wrow];
                else if (k == 51) w = W_ih0[wrow];          // W_ih0 is [4H x 1]
                h8[jj] = (_Float16)(sA * w);
            }
            a0[j][ks] = h8;
        }
        w0i[j] = widx_of(4 * (l0base + j) + q, m);
        c0[j] = 0.f;
    }

    half8 a1[NL1 ? NL1 : 1][4];            // L1: virtual K=128
    float c1[NL1 ? NL1 : 1];
    int   w1i[NL1 ? NL1 : 1];
#pragma unroll
    for (int j = 0; j < NL1; ++j) {
        const int uA = 4 * (l1base + j) + (m >> 2);   // <= 47
        const int wrow = gA * HH + uA;
#pragma unroll
        for (int ks = 0; ks < 4; ++ks) {
            half8 h8;
#pragma unroll
            for (int jj = 0; jj < 8; ++jj) {
                int k = ks * 32 + q * 8 + jj;
                float w = 0.f;
                if (k < HH)                      w = W_ih1[wrow * HH + k];
                else if (k == 50)                w = b_ih1[wrow] + b_hh1[wrow];
                else if (k >= 64 && k < 64 + HH) w = W_hh1[wrow * HH + (k - 64)];
                h8[jj] = (_Float16)(sA * w);
            }
            a1[j][ks] = h8;
        }
        w1i[j] = 1024 + widx_of(4 * (l1base + j) + q, m);
        c1[j] = 0.f;
    }

    half8 amx[4];                          // mixed tile: rows sel<2: L0 u48+sel;
    float cmx = 0.f;                       //             sel>=2: L1 u46+sel
    int   wmxi = 0;
    if (MX) {
        const int sel  = m >> 2;
        const bool lo  = (sel < 2);
        const int unit = lo ? (48 + sel) : (46 + sel);
        const int wrow = gA * HH + unit;
#pragma unroll
        for (int ks = 0; ks < 4; ++ks) {
            half8 h8;
#pragma unroll
            for (int jj = 0; jj < 8; ++jj) {
                int k = ks * 32 + q * 8 + jj;
                float w = 0.f;
                if (lo) {
                    if (k < HH)       w = W_hh0[wrow * HH + k];
                    else if (k == 50) w = b_ih0[wrow] + b_hh0[wrow];
                    else if (k == 51) w = W_ih0[wrow];
                } else {
                    if (k < HH)                      w = W_ih1[wrow * HH + k];
                    else if (k == 50)                w = b_ih1[wrow] + b_hh1[wrow];
                    else if (k >= 64 && k < 64 + HH) w = W_hh1[wrow * HH + (k - 64)];
                }
                h8[jj] = (_Float16)(sA * w);
            }
            amx[ks] = h8;
        }
        const int cu = (q < 2) ? (48 + q) : (46 + q);  // C-side unit per quad
        wmxi = ((q < 2) ? 0 : 1024) + widx_of(cu, m);
    }

    if (PRIO) __builtin_amdgcn_s_setprio(1);

    // ---- step 0: h1(0) from x(0) only -> HS[0] (h2 region stays zero) ----
    {
        const float xv = xs[m];
#pragma unroll
        for (int j = 0; j < NL0; ++j) {
            const int uC = 4 * (l0base + j) + q;
            float g4[4];
#pragma unroll
            for (int g = 0; g < 4; ++g) {
                int rg = g * HH + uC;
                g4[g] = GSC[g] * ((b_ih0[rg] + b_hh0[rg]) + W_ih0[rg] * xv);
            }
            float h = cell_update(g4[0], g4[1], g4[2], g4[3], c0[j]);
            HS[0][w0i[j]] = (_Float16)h;
        }
        if (MX) {
            if (q < 2) {                    // L0 rows only; cmx untouched on q>=2
                const int uC = 48 + q;
                float g4[4];
#pragma unroll
                for (int g = 0; g < 4; ++g) {
                    int rg = g * HH + uC;
                    g4[g] = GSC[g] * ((b_ih0[rg] + b_hh0[rg]) + W_ih0[rg] * xv);
                }
                float h = cell_update(g4[0], g4[1], g4[2], g4[3], cmx);
                HS[0][wmxi] = (_Float16)h;
            }
        }
    }
    __syncthreads();

    const floatx4 ZERO = { 0.f, 0.f, 0.f, 0.f };

    // step s (1..512): read HS[(s-1)&1]; L0 tiles -> h1(s); L1 tiles -> h2(s-1);
    // all writes -> HS[s&1]. XW writes x(s+1) into the write buffer's slot 51.
#define STEP(P, S)                                                          \
    {                                                                       \
        const _Float16* Rb = HS[(P)];                                       \
        _Float16*       Wb = HS[(P) ^ 1];                                   \
        if (XW) {                                                           \
            if (ln < 16)                                                    \
                Wb[(96 + ln) * 8 + 3] = (_Float16)xs[((S) + 1) * BT + ln];  \
        }                                                                   \
        half8 b0 = *(const half8*)&Rb[(0   + ln) * 8];                      \
        half8 b1 = *(const half8*)&Rb[(64  + ln) * 8];                      \
        half8 b2, b3;                                                       \
        if (NL1 > 0 || MX) {                                                \
            b2 = *(const half8*)&Rb[(128 + ln) * 8];                        \
            b3 = *(const half8*)&Rb[(192 + ln) * 8];                        \
        }                                                                   \
        _Pragma("unroll")                                                   \
        for (int j = 0; j < NL0; ++j) {                                     \
            floatx4 a = MFMA(a0[j][0], b0, ZERO);                           \
            a = MFMA(a0[j][1], b1, a);                                      \
            float h = cell_update(a[0], a[1], a[2], a[3], c0[j]);           \
            Wb[w0i[j]] = (_Float16)h;                                       \
        }                                                                   \
        _Pragma("unroll")                                                   \
        for (int j = 0; j < NL1; ++j) {                                     \
            floatx4 a = MFMA(a1[j][0], b0, ZERO);                           \
            a = MFMA(a1[j][1], b1, a);                                      \
            a = MFMA(a1[j][2], b2, a);                                      \
            a = MFMA(a1[j][3], b3, a);                                      \
            float h = cell_update(a[0], a[1], a[2], a[3], c1[j]);           \
            Wb[w1i[j]] = (_Float16)h;                                       \
        }                                                                   \
        if (MX) {                                                           \
            floatx4 a = MFMA(amx[0], b0, ZERO);                             \
            a = MFMA(amx[1], b1, a);                                        \
            a = MFMA(amx[2], b2, a);                                        \
            a = MFMA(amx[3], b3, a);                                        \
            float h = cell_update(a[0], a[1], a[2], a[3], cmx);             \
            Wb[wmxi] = (_Float16)h;                                         \
        }                                                                   \
        __syncthreads();                                                    \
    }

    for (int k = 0; k < 256; ++k) {
        STEP(0, 2 * k + 1);
        STEP(1, 2 * k + 2);
    }
#undef STEP
}

__global__ __launch_bounds__(NTHR, 2) void lstm_mfma(
    const float* __restrict__ x,
    const float* __restrict__ W_ih0, const float* __restrict__ W_hh0,
    const float* __restrict__ b_ih0, const float* __restrict__ b_hh0,
    const float* __restrict__ W_ih1, const float* __restrict__ W_hh1,
    const float* __restrict__ b_ih1, const float* __restrict__ b_hh1,
    const float* __restrict__ W_fc,  const float* __restrict__ b_fc,
    float* __restrict__ out)
{
    __shared__ __align__(16) _Float16 HS[2][2048];   // [ring][h1(0-63)|h2(64-127) lines]
    __shared__ float xs[(TT + 2) * BT];              // +2 zero pad rows

    const int tid = threadIdx.x;
    const int ln  = tid & 63;
    const int wv  = tid >> 6;              // 0..7
    const int b0g = blockIdx.x * BT;

    // ---------------- one-time staging ----------------
    for (int i = tid; i < BT * TT; i += NTHR) {
        int b = i & 15, t = i >> 4;
        xs[t * BT + b] = x[(size_t)(b0g + b) * TT + t];
    }
    if (tid < 2 * BT) xs[TT * BT + tid] = 0.f;
    for (int i = tid; i < 2 * 2048; i += NTHR) ((_Float16*)HS)[i] = (_Float16)0.f;
    __syncthreads();
    if (tid < 16) {
        // bias slot k=50 (line 96+n, j=2) == 1.0 in both ring buffers;
        // x(1) -> slot k=51 of HS[0] (read at step 1)
        HS[0][(96 + tid) * 8 + 2] = (_Float16)1.0f;
        HS[1][(96 + tid) * 8 + 2] = (_Float16)1.0f;
        HS[0][(96 + tid) * 8 + 3] = (_Float16)xs[BT + tid];
    }
    // (visibility: covered by run's post-prologue __syncthreads; prologue
    // writes touch disjoint addresses)

    // 25 update-calls on 8 waves; SIMD (wv&3) update counts {7,6,6,6}:
    //   w0: L0{0-3}          w4: L1{3-5}            -> SIMD0: 7 (PRIO)
    //   w1: L0{4,5} L1{0} XW w5: L0{10} L1{6,7}     -> SIMD1: 6
    //   w2: L0{6,7} L1{1}    w6: L0{11} L1{8,9}     -> SIMD2: 6
    //   w3: L0{8,9} L1{2}    w7: L1{10,11} + MIXED  -> SIMD3: 6
    switch (wv) {
    case 0: run<4, 0, false, false, true >(0,  0, ln, HS, xs, W_ih0, W_hh0, b_ih0, b_hh0, W_ih1, W_hh1, b_ih1, b_hh1); break;
    case 1: run<2, 1, false, true,  false>(4,  0, ln, HS, xs, W_ih0, W_hh0, b_ih0, b_hh0, W_ih1, W_hh1, b_ih1, b_hh1); break;
    case 2: run<2, 1, false, false, false>(6,  1, ln, HS, xs, W_ih0, W_hh0, b_ih0, b_hh0, W_ih1, W_hh1, b_ih1, b_hh1); break;
    case 3: run<2, 1, false, false, false>(8,  2, ln, HS, xs, W_ih0, W_hh0, b_ih0, b_hh0, W_ih1, W_hh1, b_ih1, b_hh1); break;
    case 4: run<0, 3, false, false, true >(0,  3, ln, HS, xs, W_ih0, W_hh0, b_ih0, b_hh0, W_ih1, W_hh1, b_ih1, b_hh1); break;
    case 5: run<1, 2, false, false, false>(10, 6, ln, HS, xs, W_ih0, W_hh0, b_ih0, b_hh0, W_ih1, W_hh1, b_ih1, b_hh1); break;
    case 6: run<1, 2, false, false, false>(11, 8, ln, HS, xs, W_ih0, W_hh0, b_ih0, b_hh0, W_ih1, W_hh1, b_ih1, b_hh1); break;
    default: run<0, 2, true, false, false>(0, 10, ln, HS, xs, W_ih0, W_hh0, b_ih0, b_hh0, W_ih1, W_hh1, b_ih1, b_hh1); break;
    }

    // -------- FC epilogue: h2(511) written at step 512 -> HS[0] h2-region --------
    if (tid < BT) {
        float a = b_fc[0];
        for (int u = 0; u < HH; ++u) {
            int idx = 1024 + ((u >> 5) * 64 + ((u >> 3) & 3) * 16 + tid) * 8 + (u & 7);
            a = fmaf((float)HS[0][idx], W_fc[u], a);
        }
        out[b0g + tid] = a;
    }
}

extern "C" void kernel_launch(void* const* d_in, const int* in_sizes, int n_in,
                              void* d_out, int out_size, void* d_ws, size_t ws_size,
                              hipStream_t stream) {
    const float* x     = (const float*)d_in[0];
    const float* W_ih0 = (const float*)d_in[1];
    const float* W_hh0 = (const float*)d_in[2];
    const float* b_ih0 = (const float*)d_in[3];
    const float* b_hh0 = (const float*)d_in[4];
    const float* W_ih1 = (const float*)d_in[5];
    const float* W_hh1 = (const float*)d_in[6];
    const float* b_ih1 = (const float*)d_in[7];
    const float* b_hh1 = (const float*)d_in[8];
    const float* W_fc  = (const float*)d_in[9];
    const float* b_fc  = (const float*)d_in[10];
    float* out = (float*)d_out;

    dim3 grid(4096 / BT);   // 256 blocks = 1/CU
    dim3 block(NTHR);       // 8 waves
    lstm_mfma<<<grid, block, 0, stream>>>(x, W_ih0, W_hh0, b_ih0, b_hh0,
                                          W_ih1, W_hh1, b_ih1, b_hh1,
                                          W_fc, b_fc, out);
}